// Round 21
// baseline (984.562 us; speedup 1.0000x reference)
//
#include <hip/hip_runtime.h>
#include <hip/hip_bf16.h>

using bf16x8 = __attribute__((ext_vector_type(8))) short;
using bf16x4 = __attribute__((ext_vector_type(4))) short;
using f32x4  = __attribute__((ext_vector_type(4))) float;

#define NE      4718592          // 36864 rows * 128
#define HALF_R  18432            // rows per side
#define HALF_E  2359296          // per-side feature elements
#define ATTN_E  3538944          // 2*48*192*192
#define SEQ     9216             // rows per linear-attn batch (4 batches)
#define NCHUNK  18
#define VSTRIDE 3088             // fullattn Vsub dblk stride in shorts (pad)
#define RB_G    3136             // raw group stride in floats (16*49*4)

typedef const unsigned int __attribute__((address_space(1)))* gas_u32;
typedef unsigned int __attribute__((address_space(3)))* las_u32;

__device__ __forceinline__ float b2f(short s) {
  union { unsigned u; float f; } x; x.u = ((unsigned)(unsigned short)s) << 16; return x.f;
}
__device__ __forceinline__ short f2b(float f) {
  __hip_bfloat16 h = __float2bfloat16(f);
  short s; __builtin_memcpy(&s, &h, 2); return s;
}
__device__ __forceinline__ f32x4 mfma16(bf16x8 a, bf16x8 b, f32x4 c) {
  return __builtin_amdgcn_mfma_f32_16x16x32_bf16(a, b, c, 0, 0, 0);
}
__device__ __forceinline__ f32x4 mfma16k16(bf16x4 a, bf16x4 b, f32x4 c) {
#if __has_builtin(__builtin_amdgcn_mfma_f32_16x16x16bf16_1k)
  return __builtin_amdgcn_mfma_f32_16x16x16bf16_1k(a, b, c, 0, 0, 0);
#else
  f32x4 d;
  asm("v_mfma_f32_16x16x16_bf16 %0, %1, %2, %3" : "=v"(d) : "v"(a), "v"(b), "v"(c));
  return d;
#endif
}

// Self-contained 12x transpose-read: waitcnt inside the asm (R9 hazard fix).
#define TR_READ12(V0,V1,V2,V3,V4,V5,V6,V7,V8,V9,V10,V11, ADDR) \
  asm volatile( \
    "ds_read_b64_tr_b16 %0, %12 offset:0\n\t" \
    "ds_read_b64_tr_b16 %1, %12 offset:512\n\t" \
    "ds_read_b64_tr_b16 %2, %12 offset:1024\n\t" \
    "ds_read_b64_tr_b16 %3, %12 offset:1536\n\t" \
    "ds_read_b64_tr_b16 %4, %12 offset:2048\n\t" \
    "ds_read_b64_tr_b16 %5, %12 offset:2560\n\t" \
    "ds_read_b64_tr_b16 %6, %12 offset:3072\n\t" \
    "ds_read_b64_tr_b16 %7, %12 offset:3584\n\t" \
    "ds_read_b64_tr_b16 %8, %12 offset:4096\n\t" \
    "ds_read_b64_tr_b16 %9, %12 offset:4608\n\t" \
    "ds_read_b64_tr_b16 %10, %12 offset:5120\n\t" \
    "ds_read_b64_tr_b16 %11, %12 offset:5632\n\t" \
    "s_waitcnt lgkmcnt(0)" \
    : "=&v"(V0), "=&v"(V1), "=&v"(V2), "=&v"(V3), "=&v"(V4), "=&v"(V5), \
      "=&v"(V6), "=&v"(V7), "=&v"(V8), "=&v"(V9), "=&v"(V10), "=&v"(V11) \
    : "v"(ADDR))

// ---------------- misc ----------------
// fp32 [6][128][128] weights -> bf16, GRANULE-PERMUTED for linear global_load_lds
__global__ void k_w2b(const float* s0, const float* s1, const float* s2, const float* s3,
                      const float* s4, const float* s5, const float* s6, const float* s7,
                      const float* s8, const float* s9, const float* s10, const float* s11,
                      short* __restrict__ dst) {
  const float* srcs[12] = {s0,s1,s2,s3,s4,s5,s6,s7,s8,s9,s10,s11};
  const float* src = srcs[blockIdx.y];
  short* d = dst + (size_t)blockIdx.y*6*16384;
  int idx = blockIdx.x*256 + threadIdx.x;      // grid.x=48 -> 12288 granules
  int layer = idx >> 11, w = idx & 2047;
  int c = w >> 4, gp = w & 15;
  int gs = gp ^ (c & 7);
  const float* s = src + layer*16384 + c*128 + gs*8;
  f32x4 v0 = *(const f32x4*)(s);
  f32x4 v1 = *(const f32x4*)(s + 4);
  short tmp[8];
  tmp[0]=f2b(v0[0]); tmp[1]=f2b(v0[1]); tmp[2]=f2b(v0[2]); tmp[3]=f2b(v0[3]);
  tmp[4]=f2b(v1[0]); tmp[5]=f2b(v1[1]); tmp[6]=f2b(v1[2]); tmp[7]=f2b(v1[3]);
  bf16x8 pk; __builtin_memcpy(&pk, tmp, 16);
  *(bf16x8*)(d + layer*16384 + c*128 + gp*8) = pk;
}

// ============ MFMA GEMM blocks ============
__device__ __forceinline__ void stage_W_async(const short* __restrict__ Wt, short* Ws,
                                              int wave, int lane) {
  #pragma unroll
  for (int is = 0; is < 8; is++) {
    int chunk = is*4 + wave;
    __builtin_amdgcn_global_load_lds((gas_u32)(const void*)(Wt + chunk*512 + lane*8),
                                     (las_u32)(void*)(Ws + chunk*512), 16, 0, 0);
  }
}
__device__ __forceinline__ void mfma_core_regA(const bf16x8 af[4], const short* Ws,
                                               int lane, f32x4 acc[8]) {
  int lrow = lane & 15, lgrp = lane >> 4;
  #pragma unroll
  for (int ct = 0; ct < 8; ct++) {
    int c = ct*16 + lrow;
    #pragma unroll
    for (int kc = 0; kc < 4; kc++) {
      int g = (kc*4 + lgrp) ^ (c & 7);
      bf16x8 wf = *(const bf16x8*)(&Ws[c*128 + g*8]);
      acc[ct] = mfma16(wf, af[kc], acc[ct]);
    }
  }
}
__device__ __forceinline__ void mfma_core_T(const short* As, const short* Ws,
                                            int wave, int lane, f32x4 acc[8]) {
  int lrow = lane & 15, lgrp = lane >> 4;
  bf16x8 af[4];
  int rl = wave*16 + lrow;
  #pragma unroll
  for (int kc = 0; kc < 4; kc++) {
    int g = (kc*4 + lgrp) ^ (rl & 7);
    af[kc] = *(const bf16x8*)(&As[rl*128 + g*8]);
  }
  mfma_core_regA(af, Ws, lane, acc);
}

// ---- standalone LN + q/k/v projections (layer 0; reads feat_l/feat_r) ----
__global__ __launch_bounds__(256) void k_qkv3(const float* __restrict__ FL,
                                              const float* __restrict__ FR,
                                              const short* __restrict__ Wq,
                                              const short* __restrict__ Wk,
                                              const short* __restrict__ Wv,
                                              const float* __restrict__ g,
                                              const float* __restrict__ b,
                                              short* __restrict__ Qo,
                                              short* __restrict__ Ko,
                                              short* __restrict__ Vo,
                                              int phi_mask, float qscale) {
  __shared__ short Ws[128*128];
  int tid = threadIdx.x;
  int row0 = blockIdx.x * 64;
  int wave = tid >> 6, lane = tid & 63;
  int lrow = lane & 15, lgrp = lane >> 4;
  int rl = wave*16 + lrow;
  int row = row0 + rl;
  const float* Fb = (row0 < HALF_R) ? FL : (FR - (size_t)HALF_E);
  stage_W_async(Wq, Ws, wave, lane);           // DMA W0 overlaps LN
  float x[4][8];
  const float* fr = Fb + (size_t)row*128;
  #pragma unroll
  for (int kc = 0; kc < 4; kc++) {
    f32x4 v0 = *(const f32x4*)(fr + kc*32 + lgrp*8);
    f32x4 v1 = *(const f32x4*)(fr + kc*32 + lgrp*8 + 4);
    x[kc][0]=v0[0]; x[kc][1]=v0[1]; x[kc][2]=v0[2]; x[kc][3]=v0[3];
    x[kc][4]=v1[0]; x[kc][5]=v1[1]; x[kc][6]=v1[2]; x[kc][7]=v1[3];
  }
  float s = 0.f, sq = 0.f;
  #pragma unroll
  for (int kc = 0; kc < 4; kc++)
    #pragma unroll
    for (int j = 0; j < 8; j++) { float xx = x[kc][j]; s += xx; sq += xx*xx; }
  s += __shfl_xor(s, 16, 64); sq += __shfl_xor(sq, 16, 64);
  s += __shfl_xor(s, 32, 64); sq += __shfl_xor(sq, 32, 64);
  float mean = s * (1.f/128.f);
  float var  = sq * (1.f/128.f) - mean*mean;
  float inv  = rsqrtf(var + 1e-5f);
  bf16x8 af[4];
  #pragma unroll
  for (int kc = 0; kc < 4; kc++) {
    int c0 = kc*32 + lgrp*8;
    f32x4 g0 = *(const f32x4*)(g + c0), g1 = *(const f32x4*)(g + c0 + 4);
    f32x4 b0 = *(const f32x4*)(b + c0), b1 = *(const f32x4*)(b + c0 + 4);
    short t8[8];
    t8[0]=f2b((x[kc][0]-mean)*inv*g0[0]+b0[0]); t8[1]=f2b((x[kc][1]-mean)*inv*g0[1]+b0[1]);
    t8[2]=f2b((x[kc][2]-mean)*inv*g0[2]+b0[2]); t8[3]=f2b((x[kc][3]-mean)*inv*g0[3]+b0[3]);
    t8[4]=f2b((x[kc][4]-mean)*inv*g1[0]+b1[0]); t8[5]=f2b((x[kc][5]-mean)*inv*g1[1]+b1[1]);
    t8[6]=f2b((x[kc][6]-mean)*inv*g1[2]+b1[2]); t8[7]=f2b((x[kc][7]-mean)*inv*g1[3]+b1[3]);
    __builtin_memcpy(&af[kc], t8, 16);
  }
  const short* Wp[3] = {Wq, Wk, Wv};
  short* Op[3] = {Qo, Ko, Vo};
  for (int y = 0; y < 3; y++) {
    __syncthreads();                           // DMA y drained
    f32x4 acc[8] = {};
    mfma_core_regA(af, Ws, lane, acc);
    bool phi = (phi_mask >> y) & 1;
    float sc = (y == 0) ? qscale : 1.0f;
    short* OUT = Op[y] + (size_t)row*128 + lgrp*4;
    __syncthreads();                           // all waves done reading Ws
    if (y < 2) stage_W_async(Wp[y+1], Ws, wave, lane);
    #pragma unroll
    for (int ct = 0; ct < 8; ct++) {
      short t4[4];
      #pragma unroll
      for (int reg = 0; reg < 4; reg++) {
        float v = acc[ct][reg] * sc;
        if (phi) v = (v > 0.f) ? v + 1.0f : __expf(v);
        t4[reg] = f2b(v);
      }
      bf16x4 pk; __builtin_memcpy(&pk, t4, 8);
      *(bf16x4*)(OUT + ct*16) = pk;
    }
  }
}

// ---- shared MLP tail; optional fused next-projection (QKV) ----
template<bool REGA, bool QKV>
__device__ __forceinline__ void mlp_tail(const bf16x8 af1[4], short* As, short* Ws,
                                         const short* __restrict__ W1,
                                         const short* __restrict__ W2,
                                         const float* __restrict__ g,
                                         const float* __restrict__ b,
                                         const float* __restrict__ Fin,
                                         float* __restrict__ Fout,
                                         int row0, int tid,
                                         const float* __restrict__ n1g,
                                         const float* __restrict__ n1b,
                                         const short* __restrict__ Wq,
                                         const short* __restrict__ Wk,
                                         const short* __restrict__ Wv,
                                         short* __restrict__ Qo,
                                         short* __restrict__ Ko,
                                         short* __restrict__ Vo,
                                         int phi_mask, float qscale) {
  int wave = tid >> 6, lane = tid & 63;
  int lrow = lane & 15, lgrp = lane >> 4;
  int rl = wave*16 + lrow;
  int orow = row0 + rl;
  const float* Fri = Fin + (size_t)orow*128 + lgrp*4;
  float* Fro = Fout + (size_t)orow*128 + lgrp*4;
  f32x4 acc[8] = {};
  if (REGA) mfma_core_regA(af1, Ws, lane, acc);
  else      mfma_core_T(As, Ws, wave, lane, acc);
  f32x4 fnew[8];
  #pragma unroll
  for (int ct = 0; ct < 8; ct++) {
    f32x4 fv = *(const f32x4*)(Fri + ct*16);
    fnew[ct] = acc[ct] + fv;
  }
  float s = 0.f, sq = 0.f;
  #pragma unroll
  for (int ct = 0; ct < 8; ct++)
    #pragma unroll
    for (int reg = 0; reg < 4; reg++) { float x = fnew[ct][reg]; s += x; sq += x*x; }
  s += __shfl_xor(s, 16, 64); sq += __shfl_xor(sq, 16, 64);
  s += __shfl_xor(s, 32, 64); sq += __shfl_xor(sq, 32, 64);
  float mean = s * (1.f/128.f);
  float var  = sq * (1.f/128.f) - mean*mean;
  float inv  = rsqrtf(var + 1e-5f);
  __syncthreads();                         // all waves done with Ws (GEMM1)
  stage_W_async(W1, Ws, wave, lane);
  #pragma unroll
  for (int ct = 0; ct < 8; ct++) {
    short t4[4];
    #pragma unroll
    for (int reg = 0; reg < 4; reg++) {
      int c = ct*16 + lgrp*4 + reg;
      t4[reg] = f2b((fnew[ct][reg] - mean) * inv * g[c] + b[c]);
    }
    bf16x4 pk; __builtin_memcpy(&pk, t4, 8);
    int G = ct*2 + (lgrp >> 1);
    *(bf16x4*)(&As[rl*128 + ((G ^ (rl & 7))*8) + (lgrp & 1)*4]) = pk;
  }
  __syncthreads();                         // DMA W1 drained + As visible
  f32x4 acc2[8] = {};
  mfma_core_T(As, Ws, wave, lane, acc2);
  __syncthreads();                         // done reading Ws/As (GEMM2)
  stage_W_async(W2, Ws, wave, lane);
  #pragma unroll
  for (int ct = 0; ct < 8; ct++) {
    short t4[4];
    #pragma unroll
    for (int reg = 0; reg < 4; reg++) {
      float v = acc2[ct][reg];
      v = 0.5f*v*(1.0f + erff(v*0.70710678118654752f));
      t4[reg] = f2b(v);
    }
    bf16x4 pk; __builtin_memcpy(&pk, t4, 8);
    int G = ct*2 + (lgrp >> 1);
    *(bf16x4*)(&As[rl*128 + ((G ^ (rl & 7))*8) + (lgrp & 1)*4]) = pk;
  }
  __syncthreads();                         // As visible; drains W2
  f32x4 acc3[8] = {};
  mfma_core_T(As, Ws, wave, lane, acc3);
  f32x4 o8[8];
  #pragma unroll
  for (int ct = 0; ct < 8; ct++) {
    o8[ct] = fnew[ct] + acc3[ct];
    *(f32x4*)(Fro + ct*16) = o8[ct];
  }
  if (QKV) {
    // next-stage LN (n1) fully in-register over the new F rows
    float s2 = 0.f, sq2 = 0.f;
    #pragma unroll
    for (int ct = 0; ct < 8; ct++)
      #pragma unroll
      for (int reg = 0; reg < 4; reg++) { float x = o8[ct][reg]; s2 += x; sq2 += x*x; }
    s2 += __shfl_xor(s2, 16, 64); sq2 += __shfl_xor(sq2, 16, 64);
    s2 += __shfl_xor(s2, 32, 64); sq2 += __shfl_xor(sq2, 32, 64);
    float mean2 = s2 * (1.f/128.f);
    float var2  = sq2 * (1.f/128.f) - mean2*mean2;
    float inv2  = rsqrtf(var2 + 1e-5f);
    __syncthreads();                       // all waves done reading As/Ws (GEMM3)
    stage_W_async(Wq, Ws, wave, lane);
    #pragma unroll
    for (int ct = 0; ct < 8; ct++) {
      short t4[4];
      #pragma unroll
      for (int reg = 0; reg < 4; reg++) {
        int c = ct*16 + lgrp*4 + reg;
        t4[reg] = f2b((o8[ct][reg] - mean2) * inv2 * n1g[c] + n1b[c]);
      }
      bf16x4 pk; __builtin_memcpy(&pk, t4, 8);
      int G = ct*2 + (lgrp >> 1);
      *(bf16x4*)(&As[rl*128 + ((G ^ (rl & 7))*8) + (lgrp & 1)*4]) = pk;
    }
    __syncthreads();                       // Wq drained + As visible
    bf16x8 af[4];
    #pragma unroll
    for (int kc = 0; kc < 4; kc++) {
      int g2 = (kc*4 + lgrp) ^ (rl & 7);
      af[kc] = *(const bf16x8*)(&As[rl*128 + g2*8]);
    }
    const short* Wp[3] = {Wq, Wk, Wv};
    short* Op[3] = {Qo, Ko, Vo};
    for (int y = 0; y < 3; y++) {
      if (y > 0) __syncthreads();          // drain DMA y
      f32x4 accq[8] = {};
      mfma_core_regA(af, Ws, lane, accq);
      __syncthreads();                     // all waves done reading Ws
      if (y < 2) stage_W_async(Wp[y+1], Ws, wave, lane);
      bool phi = (phi_mask >> y) & 1;
      float sc = (y == 0) ? qscale : 1.0f;
      short* OUT = Op[y] + (size_t)orow*128 + lgrp*4;
      #pragma unroll
      for (int ct = 0; ct < 8; ct++) {
        short t4[4];
        #pragma unroll
        for (int reg = 0; reg < 4; reg++) {
          float v = accq[ct][reg] * sc;
          if (phi) v = (v > 0.f) ? v + 1.0f : __expf(v);
          t4[reg] = f2b(v);
        }
        bf16x4 pk; __builtin_memcpy(&pk, t4, 8);
        *(bf16x4*)(OUT + ct*16) = pk;
      }
    }
  }
}

// cross-layer MLP (last layer): Msg from global, Fout = d_out
__global__ __launch_bounds__(256) void k_mlp(const short* __restrict__ Msg,
                                             const short* __restrict__ Wm,
                                             const short* __restrict__ W1,
                                             const short* __restrict__ W2,
                                             const float* __restrict__ g,
                                             const float* __restrict__ b,
                                             const float* __restrict__ Fin,
                                             float* __restrict__ Fout) {
  __shared__ short As[64*128];
  __shared__ short Ws[128*128];
  int tid = threadIdx.x;
  int row0 = blockIdx.x * 64;
  int wave = tid >> 6, lane = tid & 63;
  int lgrp = lane >> 4;
  int row = row0 + wave*16 + (lane & 15);
  stage_W_async(Wm, Ws, wave, lane);
  bf16x8 af1[4];
  const short* mr = Msg + (size_t)row*128;
  #pragma unroll
  for (int kc = 0; kc < 4; kc++)
    af1[kc] = *(const bf16x8*)(mr + kc*32 + lgrp*8);
  __syncthreads();
  mlp_tail<true, false>(af1, As, Ws, W1, W2, g, b, Fin, Fout, row0, tid,
                        nullptr, nullptr, nullptr, nullptr, nullptr,
                        nullptr, nullptr, nullptr, 0, 0.f);
}

// cross-layer MLP + next layer's self q/k/v projections fused
__global__ __launch_bounds__(256) void k_mlp_qkv(const short* __restrict__ Msg,
                                                 const short* __restrict__ Wm,
                                                 const short* __restrict__ W1,
                                                 const short* __restrict__ W2,
                                                 const float* __restrict__ g,
                                                 const float* __restrict__ b,
                                                 const float* __restrict__ Fin,
                                                 float* __restrict__ Fout,
                                                 const float* __restrict__ n1g,
                                                 const float* __restrict__ n1b,
                                                 const short* __restrict__ Wq,
                                                 const short* __restrict__ Wk,
                                                 const short* __restrict__ Wv,
                                                 short* __restrict__ Qo,
                                                 short* __restrict__ Ko,
                                                 short* __restrict__ Vo) {
  __shared__ short As[64*128];
  __shared__ short Ws[128*128];
  int tid = threadIdx.x;
  int row0 = blockIdx.x * 64;
  int wave = tid >> 6, lane = tid & 63;
  int lgrp = lane >> 4;
  int row = row0 + wave*16 + (lane & 15);
  stage_W_async(Wm, Ws, wave, lane);
  bf16x8 af1[4];
  const short* mr = Msg + (size_t)row*128;
  #pragma unroll
  for (int kc = 0; kc < 4; kc++)
    af1[kc] = *(const bf16x8*)(mr + kc*32 + lgrp*8);
  __syncthreads();
  mlp_tail<true, true>(af1, As, Ws, W1, W2, g, b, Fin, Fout, row0, tid,
                       n1g, n1b, Wq, Wk, Wv, Qo, Ko, Vo, 0b011, 1.0f);
}

// self-layer MLP (linear-attn apply fused) + cross q/k/v projections fused
__global__ __launch_bounds__(256) void k_mlpself_qkv(const short* __restrict__ Q,
                                                     const float* __restrict__ kvp,
                                                     const short* __restrict__ Wm,
                                                     const short* __restrict__ W1,
                                                     const short* __restrict__ W2,
                                                     const float* __restrict__ g,
                                                     const float* __restrict__ b,
                                                     const float* __restrict__ FL,
                                                     const float* __restrict__ FR,
                                                     float* __restrict__ Fout,
                                                     const float* __restrict__ n1g,
                                                     const float* __restrict__ n1b,
                                                     const short* __restrict__ Wq,
                                                     const short* __restrict__ Wk,
                                                     const short* __restrict__ Wv,
                                                     short* __restrict__ Qo,
                                                     short* __restrict__ Ko,
                                                     short* __restrict__ Vo) {
  __shared__ short As[64*128];
  __shared__ short Ws[128*128];
  __shared__ float kvs[8*273];
  int tid = threadIdx.x;
  int row0 = blockIdx.x * 64;
  int n = row0 / SEQ;
  const float* Fin = (row0 < HALF_R) ? FL : (FR - (size_t)HALF_E);
  stage_W_async(Wm, Ws, tid >> 6, tid & 63);
  for (int i = tid; i < 8*272; i += 256) {
    int h = i / 272, j = i % 272;
    const float* src = kvp + ((size_t)(n*8 + h)*NCHUNK)*272 + j;
    float s = 0.f;
    #pragma unroll
    for (int c2 = 0; c2 < NCHUNK; c2++) s += src[(size_t)c2*272];
    kvs[h*273 + j] = s;
  }
  __syncthreads();
  int r = tid >> 2, qq = tid & 3;
  const short* qr = Q + (size_t)(row0 + r)*128;
  #pragma unroll
  for (int hh = 0; hh < 2; hh++) {
    int h = qq*2 + hh;
    bf16x8 q0 = *(const bf16x8*)(qr + h*16);
    bf16x8 q1 = *(const bf16x8*)(qr + h*16 + 8);
    float q[16];
    #pragma unroll
    for (int j = 0; j < 8; j++) { q[j] = b2f(q0[j]); q[8+j] = b2f(q1[j]); }
    const float* kvh = kvs + h*273;
    float z = 1e-6f;
    #pragma unroll
    for (int d = 0; d < 16; d++) z += q[d] * kvh[256 + d];
    float invz = 1.f / z;
    short o16[16];
    #pragma unroll
    for (int d2 = 0; d2 < 16; d2++) {
      float o = 0.f;
      #pragma unroll
      for (int d = 0; d < 16; d++) o += q[d] * kvh[d*16 + d2];
      o16[d2] = f2b(o * invz);
    }
    bf16x8 lo, hi; __builtin_memcpy(&lo, o16, 16); __builtin_memcpy(&hi, o16+8, 16);
    *(bf16x8*)(&As[r*128 + (((2*h)   ^ (r & 7))*8)]) = lo;
    *(bf16x8*)(&As[r*128 + (((2*h+1) ^ (r & 7))*8)]) = hi;
  }
  __syncthreads();
  mlp_tail<false, true>(nullptr, As, Ws, W1, W2, g, b, Fin, Fout, row0, tid,
                        n1g, n1b, Wq, Wk, Wv, Qo, Ko, Vo, 0, 0.25f);
}

// ---------------- linear attention: KV partial reduce (64-row coalesced tiles) ----
__global__ __launch_bounds__(256) void k_linred(const short* __restrict__ K,
                                                const short* __restrict__ V,
                                                float* __restrict__ kvp) {
  int nh = blockIdx.x;
  int n = nh >> 3, h = nh & 7;
  int chunk = blockIdx.y;
  int r0 = chunk * (SEQ / NCHUNK);          // 512 rows per chunk
  __shared__ float ks[64][17], vs[64][17];
  int tid = threadIdx.x;
  int d1 = tid >> 4, d2 = tid & 15;
  int rr = tid >> 2, q = tid & 3;
  float kv = 0.f, ksum = 0.f;
  for (int r = r0; r < r0 + SEQ/NCHUNK; r += 64) {
    __syncthreads();
    bf16x4 kk = *(const bf16x4*)(K + (size_t)(n*SEQ + r + rr)*128 + h*16 + q*4);
    bf16x4 vv = *(const bf16x4*)(V + (size_t)(n*SEQ + r + rr)*128 + h*16 + q*4);
    #pragma unroll
    for (int j = 0; j < 4; j++) { ks[rr][q*4+j] = b2f(kk[j]); vs[rr][q*4+j] = b2f(vv[j]); }
    __syncthreads();
    #pragma unroll
    for (int j = 0; j < 64; j++) {
      float kvl = ks[j][d1];
      kv   += kvl * vs[j][d2];
      ksum += kvl;
    }
  }
  float* dst = kvp + ((size_t)nh*NCHUNK + chunk)*272;
  dst[d1*16 + d2] = kv;
  if (d2 == 0) dst[256 + d1] = ksum;
}

// ------- full attention: 8 waves x 1 head; coalesced raw; XCD swizzle ----
__global__ __launch_bounds__(512, 4) void k_fullattn(const short* __restrict__ Q,
                                                     const short* __restrict__ K,
                                                     const short* __restrict__ V,
                                                     short* __restrict__ MSG,
                                                     const float* __restrict__ RSL,
                                                     const float* __restrict__ RSR,
                                                     float* __restrict__ RDL,
                                                     float* __restrict__ RDR,
                                                     const float* __restrict__ ATL,
                                                     const float* __restrict__ ATR,
                                                     int first, int last) {
  __shared__ __attribute__((aligned(16))) char smem[4*RB_G*4];  // 50.2KB union
  short* Vsub = (short*)smem;
  float* rawb = (float*)smem;
  int flat = blockIdx.x;
  int xcd = flat & 7, slot = flat >> 3;      // slot 0..95
  int group = xcd*24 + (slot >> 2);          // 0..191
  int part = slot & 3;
  int side = group >= 96 ? 1 : 0;
  int n = group - side*96;
  int qbase = side*HALF_R + n*192;
  int kbase = (side^1)*HALF_R + n*192;
  const float* rsb = (side ? RSR : RSL) + (size_t)n*192*192;
  float* rdb = (side ? RDR : RDL) + (size_t)n*192*192;
  const float* atb = (side ? ATR : ATL) + (size_t)n*192*192;
  int tid = threadIdx.x;
  int wave = tid >> 6, lane = tid & 63;   // wave = head
  int lrow = lane & 15, lgrp = lane >> 4;

  #pragma unroll
  for (int i = 0; i < 6; i++) {
    int c = tid + 512*i;
    int s = c >> 4, t8 = c & 15;
    bf16x8 v8 = *(const bf16x8*)(V + (size_t)(kbase + s)*128 + t8*8);
    *(bf16x8*)(&Vsub[(t8 >> 1)*VSTRIDE + s*16 + (t8 & 1)*8]) = v8;
  }
  __syncthreads();

  bf16x4 vf[12];
  {
    unsigned va = (unsigned)(uintptr_t)(&Vsub[0]) + wave*(VSTRIDE*2) + lane*8;
    TR_READ12(vf[0], vf[1], vf[2], vf[3], vf[4], vf[5],
              vf[6], vf[7], vf[8], vf[9], vf[10], vf[11], va);
  }
  __builtin_amdgcn_sched_barrier(0);
  bf16x4 kfr[12];
  #pragma unroll
  for (int st = 0; st < 12; st++)
    kfr[st] = *(const bf16x4*)(K + (size_t)(kbase + st*16 + lrow)*128
                                 + wave*16 + lgrp*4);
  __syncthreads();                   // Vsub consumed; smem becomes rawb

  const f32x4 z4 = {0.f, 0.f, 0.f, 0.f};
  int g = wave & 3;
  for (int li = 0; li < 3; li++) {
    int l0 = (part*3 + li)*16;
    bf16x4 qf = *(const bf16x4*)(Q + (size_t)(qbase + l0 + lrow)*128 + wave*16 + lgrp*4);
    f32x4 sa[12];
    #pragma unroll
    for (int st = 0; st < 12; st++)
      sa[st] = mfma16k16(kfr[st], qf, z4);
    float m = -1e30f;
    #pragma unroll
    for (int st = 0; st < 12; st++)
      m = fmaxf(m, fmaxf(fmaxf(sa[st][0], sa[st][1]), fmaxf(sa[st][2], sa[st][3])));
    m = fmaxf(m, __shfl_xor(m, 16, 64));
    m = fmaxf(m, __shfl_xor(m, 32, 64));
    float sum = 0.f;
    #pragma unroll
    for (int st = 0; st < 12; st++) {
      #pragma unroll
      for (int r = 0; r < 4; r++) {
        float p = __expf(sa[st][r] - m);
        sa[st][r] = p; sum += p;
      }
    }
    sum += __shfl_xor(sum, 16, 64);
    sum += __shfl_xor(sum, 32, 64);
    float inv = 1.f / sum;
    #pragma unroll
    for (int st = 0; st < 12; st++) {
      sa[st][0] *= inv; sa[st][1] *= inv; sa[st][2] *= inv; sa[st][3] *= inv;
    }
    {
      f32x4 o = z4;
      #pragma unroll
      for (int st = 0; st < 12; st++) {
        bf16x4 pf;
        pf[0] = f2b(sa[st][0]); pf[1] = f2b(sa[st][1]);
        pf[2] = f2b(sa[st][2]); pf[3] = f2b(sa[st][3]);
        o = mfma16k16(vf[st], pf, o);
      }
      bf16x4 o4;
      o4[0] = f2b(o[0]); o4[1] = f2b(o[1]); o4[2] = f2b(o[2]); o4[3] = f2b(o[3]);
      *(bf16x4*)(MSG + (size_t)(qbase + l0 + lrow)*128 + wave*16 + lgrp*4) = o4;
    }
    if (wave < 4) {
      #pragma unroll
      for (int st = 0; st < 12; st++)
        *(f32x4*)(&rawb[g*RB_G + (lrow*49 + st*4 + lgrp)*4]) = sa[st];
    }
    __syncthreads();
    if (wave >= 4) {
      #pragma unroll
      for (int st = 0; st < 12; st++) {
        f32x4* slot2 = (f32x4*)(&rawb[g*RB_G + (lrow*49 + st*4 + lgrp)*4]);
        *slot2 = *slot2 + sa[st];
      }
    }
    __syncthreads();
    #pragma unroll
    for (int i = 0; i < 2; i++) {
      int sl = tid + 512*i;
      if (sl < 768) {
        int row = sl / 48, grp = sl - row*48;
        int off = (row*49 + grp)*4;
        f32x4 a = *(const f32x4*)(&rawb[0*RB_G + off]);
        f32x4 b = *(const f32x4*)(&rawb[1*RB_G + off]);
        f32x4 c = *(const f32x4*)(&rawb[2*RB_G + off]);
        f32x4 d = *(const f32x4*)(&rawb[3*RB_G + off]);
        f32x4 t = (a + b) + (c + d);
        size_t goff = (size_t)(l0 + row)*192 + grp*4;
        if (!first) t = t + *(const f32x4*)(rsb + goff);
        if (last)   t = t + *(const f32x4*)(atb + goff);
        *(f32x4*)(rdb + goff) = t;
      }
    }
    __syncthreads();
  }
}

// ---------------- launch ----------------
extern "C" void kernel_launch(void* const* d_in, const int* in_sizes, int n_in,
                              void* d_out, int out_size, void* d_ws, size_t ws_size,
                              hipStream_t stream) {
  const float* feat_l = (const float*)d_in[0];
  const float* feat_r = (const float*)d_in[1];
  const float* attn_l = (const float*)d_in[2];
  const float* attn_r = (const float*)d_in[3];
  const float* saw[6] = { (const float*)d_in[4],  (const float*)d_in[6],  (const float*)d_in[8],
                          (const float*)d_in[10], (const float*)d_in[12], (const float*)d_in[14] };
  const float* caw[6] = { (const float*)d_in[5],  (const float*)d_in[7],  (const float*)d_in[9],
                          (const float*)d_in[11], (const float*)d_in[13], (const float*)d_in[15] };
  const float* sa_n1g = (const float*)d_in[16]; const float* ca_n1g = (const float*)d_in[17];
  const float* sa_n1b = (const float*)d_in[18]; const float* ca_n1b = (const float*)d_in[19];
  const float* sa_n2g = (const float*)d_in[20]; const float* ca_n2g = (const float*)d_in[21];
  const float* sa_n2b = (const float*)d_in[22]; const float* ca_n2b = (const float*)d_in[23];

  float* F   = (float*)d_ws;
  float* ALa = F + NE;
  float* ARa = ALa + ATTN_E;
  float* KVp = ARa + ATTN_E;                   // 32*NCHUNK*272
  short* WB  = (short*)(KVp + 32*NCHUNK*272);
  short* Qb  = WB + 12*6*16384;
  short* Kb  = Qb + NE;
  short* Vb  = Kb + NE;
  short* Mb  = Vb + NE;

  float* out = (float*)d_out;

  k_w2b<<<dim3(48,12), 256, 0, stream>>>(saw[0],saw[1],saw[2],saw[3],saw[4],saw[5],
                                         caw[0],caw[1],caw[2],caw[3],caw[4],caw[5], WB);

  // layer 0 self q/k/v from input features
  {
    const short* sw0[3] = { WB + (size_t)(0*6 + 0)*16384,
                            WB + (size_t)(1*6 + 0)*16384,
                            WB + (size_t)(2*6 + 0)*16384 };
    k_qkv3<<<576, 256, 0, stream>>>(feat_l, feat_r, sw0[0], sw0[1], sw0[2],
                                    sa_n1g, sa_n1b, Qb, Kb, Vb, 0b011, 1.0f);
  }

  for (int i = 0; i < 6; i++) {
    const short* sw[6], *cw[6];
    for (int t = 0; t < 6; t++) { sw[t] = WB + (size_t)(t*6 + i)*16384; cw[t] = WB + (size_t)((6+t)*6 + i)*16384; }
    int vo = i*128;
    const float* FL = (i == 0) ? feat_l : F;
    const float* FR = (i == 0) ? feat_r : (F + HALF_E);
    // ---- self layer: linred + (mlp_self + cross-qkv fused) ----
    k_linred<<<dim3(32, NCHUNK), 256, 0, stream>>>(Kb, Vb, KVp);
    k_mlpself_qkv<<<576, 256, 0, stream>>>(Qb, KVp, sw[3], sw[4], sw[5],
                                           sa_n2g+vo, sa_n2b+vo, FL, FR, F,
                                           ca_n1g+vo, ca_n1b+vo,
                                           cw[0], cw[1], cw[2], Qb, Kb, Vb);
    // ---- cross layer ----
    int last = (i == 5);
    k_fullattn<<<768, 512, 0, stream>>>(Qb, Kb, Vb, Mb,
                                        ALa, ARa,
                                        last ? out + NE : ALa,
                                        last ? out + NE + ATTN_E : ARa,
                                        attn_l, attn_r,
                                        i == 0 ? 1 : 0, last);
    if (!last) {
      const short* swn[3] = { WB + (size_t)(0*6 + i+1)*16384,
                              WB + (size_t)(1*6 + i+1)*16384,
                              WB + (size_t)(2*6 + i+1)*16384 };
      k_mlp_qkv<<<576, 256, 0, stream>>>(Mb, cw[3], cw[4], cw[5],
                                         ca_n2g+vo, ca_n2b+vo, F, F,
                                         sa_n1g+(i+1)*128, sa_n1b+(i+1)*128,
                                         swn[0], swn[1], swn[2], Qb, Kb, Vb);
    } else {
      k_mlp<<<576, 256, 0, stream>>>(Mb, cw[3], cw[4], cw[5],
                                     ca_n2g+vo, ca_n2b+vo, F, out);
    }
  }
}

// Round 22
// 970.169 us; speedup vs baseline: 1.0148x; 1.0148x over previous
//
#include <hip/hip_runtime.h>
#include <hip/hip_bf16.h>

using bf16x8 = __attribute__((ext_vector_type(8))) short;
using bf16x4 = __attribute__((ext_vector_type(4))) short;
using f32x4  = __attribute__((ext_vector_type(4))) float;

#define NE      4718592          // 36864 rows * 128
#define HALF_R  18432            // rows per side
#define ATTN_E  3538944          // 2*48*192*192
#define SEQ     9216             // rows per linear-attn batch (4 batches)
#define NCHUNK  18
#define VSTRIDE 3088             // fullattn Vsub dblk stride in shorts (pad)
#define RB_G    3136             // raw group stride in floats (16*49*4)

typedef const unsigned int __attribute__((address_space(1)))* gas_u32;
typedef unsigned int __attribute__((address_space(3)))* las_u32;

__device__ __forceinline__ float b2f(short s) {
  union { unsigned u; float f; } x; x.u = ((unsigned)(unsigned short)s) << 16; return x.f;
}
__device__ __forceinline__ short f2b(float f) {
  __hip_bfloat16 h = __float2bfloat16(f);
  short s; __builtin_memcpy(&s, &h, 2); return s;
}
__device__ __forceinline__ f32x4 mfma16(bf16x8 a, bf16x8 b, f32x4 c) {
  return __builtin_amdgcn_mfma_f32_16x16x32_bf16(a, b, c, 0, 0, 0);
}
__device__ __forceinline__ f32x4 mfma16k16(bf16x4 a, bf16x4 b, f32x4 c) {
#if __has_builtin(__builtin_amdgcn_mfma_f32_16x16x16bf16_1k)
  return __builtin_amdgcn_mfma_f32_16x16x16bf16_1k(a, b, c, 0, 0, 0);
#else
  f32x4 d;
  asm("v_mfma_f32_16x16x16_bf16 %0, %1, %2, %3" : "=v"(d) : "v"(a), "v"(b), "v"(c));
  return d;
#endif
}

// Self-contained 12x transpose-read: waitcnt inside the asm (R9 hazard fix).
#define TR_READ12(V0,V1,V2,V3,V4,V5,V6,V7,V8,V9,V10,V11, ADDR) \
  asm volatile( \
    "ds_read_b64_tr_b16 %0, %12 offset:0\n\t" \
    "ds_read_b64_tr_b16 %1, %12 offset:512\n\t" \
    "ds_read_b64_tr_b16 %2, %12 offset:1024\n\t" \
    "ds_read_b64_tr_b16 %3, %12 offset:1536\n\t" \
    "ds_read_b64_tr_b16 %4, %12 offset:2048\n\t" \
    "ds_read_b64_tr_b16 %5, %12 offset:2560\n\t" \
    "ds_read_b64_tr_b16 %6, %12 offset:3072\n\t" \
    "ds_read_b64_tr_b16 %7, %12 offset:3584\n\t" \
    "ds_read_b64_tr_b16 %8, %12 offset:4096\n\t" \
    "ds_read_b64_tr_b16 %9, %12 offset:4608\n\t" \
    "ds_read_b64_tr_b16 %10, %12 offset:5120\n\t" \
    "ds_read_b64_tr_b16 %11, %12 offset:5632\n\t" \
    "s_waitcnt lgkmcnt(0)" \
    : "=&v"(V0), "=&v"(V1), "=&v"(V2), "=&v"(V3), "=&v"(V4), "=&v"(V5), \
      "=&v"(V6), "=&v"(V7), "=&v"(V8), "=&v"(V9), "=&v"(V10), "=&v"(V11) \
    : "v"(ADDR))

// ---------------- misc ----------------
__global__ void k_copy(const float* __restrict__ in, float* __restrict__ out, int n) {
  for (int i = blockIdx.x*blockDim.x + threadIdx.x; i < n; i += gridDim.x*blockDim.x)
    out[i] = in[i];
}
__global__ void k_addf(const float* __restrict__ base, const float* __restrict__ acc,
                       float* __restrict__ out, int n) {
  for (int i = blockIdx.x*blockDim.x + threadIdx.x; i < n; i += gridDim.x*blockDim.x)
    out[i] = base[i] + acc[i];
}
// fp32 [6][128][128] weights -> bf16, GRANULE-PERMUTED for linear global_load_lds
__global__ void k_w2b(const float* s0, const float* s1, const float* s2, const float* s3,
                      const float* s4, const float* s5, const float* s6, const float* s7,
                      const float* s8, const float* s9, const float* s10, const float* s11,
                      short* __restrict__ dst) {
  const float* srcs[12] = {s0,s1,s2,s3,s4,s5,s6,s7,s8,s9,s10,s11};
  const float* src = srcs[blockIdx.y];
  short* d = dst + (size_t)blockIdx.y*6*16384;
  int idx = blockIdx.x*256 + threadIdx.x;      // grid.x=48 -> 12288 granules
  int layer = idx >> 11, w = idx & 2047;
  int c = w >> 4, gp = w & 15;
  int gs = gp ^ (c & 7);
  const float* s = src + layer*16384 + c*128 + gs*8;
  f32x4 v0 = *(const f32x4*)(s);
  f32x4 v1 = *(const f32x4*)(s + 4);
  short tmp[8];
  tmp[0]=f2b(v0[0]); tmp[1]=f2b(v0[1]); tmp[2]=f2b(v0[2]); tmp[3]=f2b(v0[3]);
  tmp[4]=f2b(v1[0]); tmp[5]=f2b(v1[1]); tmp[6]=f2b(v1[2]); tmp[7]=f2b(v1[3]);
  bf16x8 pk; __builtin_memcpy(&pk, tmp, 16);
  *(bf16x8*)(d + layer*16384 + c*128 + gp*8) = pk;
}

// ============ MFMA GEMM blocks ============
__device__ __forceinline__ void stage_W_async(const short* __restrict__ Wt, short* Ws,
                                              int wave, int lane) {
  #pragma unroll
  for (int is = 0; is < 8; is++) {
    int chunk = is*4 + wave;
    __builtin_amdgcn_global_load_lds((gas_u32)(const void*)(Wt + chunk*512 + lane*8),
                                     (las_u32)(void*)(Ws + chunk*512), 16, 0, 0);
  }
}
// reg-A MFMA core: af passed in registers; W frags from swizzled LDS
__device__ __forceinline__ void mfma_core_regA(const bf16x8 af[4], const short* Ws,
                                               int lane, f32x4 acc[8]) {
  int lrow = lane & 15, lgrp = lane >> 4;
  #pragma unroll
  for (int ct = 0; ct < 8; ct++) {
    int c = ct*16 + lrow;
    #pragma unroll
    for (int kc = 0; kc < 4; kc++) {
      int g = (kc*4 + lgrp) ^ (c & 7);
      bf16x8 wf = *(const bf16x8*)(&Ws[c*128 + g*8]);
      acc[ct] = mfma16(wf, af[kc], acc[ct]);
    }
  }
}
// LDS-A MFMA core (As XOR-swizzled)
__device__ __forceinline__ void mfma_core_T(const short* As, const short* Ws,
                                            int wave, int lane, f32x4 acc[8]) {
  int lrow = lane & 15, lgrp = lane >> 4;
  bf16x8 af[4];
  int rl = wave*16 + lrow;
  #pragma unroll
  for (int kc = 0; kc < 4; kc++) {
    int g = (kc*4 + lgrp) ^ (rl & 7);
    af[kc] = *(const bf16x8*)(&As[rl*128 + g*8]);
  }
  mfma_core_regA(af, Ws, lane, acc);
}

// ---- fused LN + q/k/v projections: in-register LN, DMA-pipelined Ws (R15) ----
__global__ __launch_bounds__(256) void k_qkv3(const float* __restrict__ F,
                                              const short* __restrict__ Wq,
                                              const short* __restrict__ Wk,
                                              const short* __restrict__ Wv,
                                              const float* __restrict__ g,
                                              const float* __restrict__ b,
                                              short* __restrict__ Qo,
                                              short* __restrict__ Ko,
                                              short* __restrict__ Vo,
                                              int phi_mask, float qscale) {
  __shared__ short Ws[128*128];
  int tid = threadIdx.x;
  int row0 = blockIdx.x * 64;
  int wave = tid >> 6, lane = tid & 63;
  int lrow = lane & 15, lgrp = lane >> 4;
  int rl = wave*16 + lrow;
  int row = row0 + rl;
  stage_W_async(Wq, Ws, wave, lane);           // DMA W0 overlaps LN
  float x[4][8];
  const float* fr = F + (size_t)row*128;
  #pragma unroll
  for (int kc = 0; kc < 4; kc++) {
    f32x4 v0 = *(const f32x4*)(fr + kc*32 + lgrp*8);
    f32x4 v1 = *(const f32x4*)(fr + kc*32 + lgrp*8 + 4);
    x[kc][0]=v0[0]; x[kc][1]=v0[1]; x[kc][2]=v0[2]; x[kc][3]=v0[3];
    x[kc][4]=v1[0]; x[kc][5]=v1[1]; x[kc][6]=v1[2]; x[kc][7]=v1[3];
  }
  float s = 0.f, sq = 0.f;
  #pragma unroll
  for (int kc = 0; kc < 4; kc++)
    #pragma unroll
    for (int j = 0; j < 8; j++) { float xx = x[kc][j]; s += xx; sq += xx*xx; }
  s += __shfl_xor(s, 16, 64); sq += __shfl_xor(sq, 16, 64);
  s += __shfl_xor(s, 32, 64); sq += __shfl_xor(sq, 32, 64);
  float mean = s * (1.f/128.f);
  float var  = sq * (1.f/128.f) - mean*mean;
  float inv  = rsqrtf(var + 1e-5f);
  bf16x8 af[4];
  #pragma unroll
  for (int kc = 0; kc < 4; kc++) {
    int c0 = kc*32 + lgrp*8;
    f32x4 g0 = *(const f32x4*)(g + c0), g1 = *(const f32x4*)(g + c0 + 4);
    f32x4 b0 = *(const f32x4*)(b + c0), b1 = *(const f32x4*)(b + c0 + 4);
    short t8[8];
    t8[0]=f2b((x[kc][0]-mean)*inv*g0[0]+b0[0]); t8[1]=f2b((x[kc][1]-mean)*inv*g0[1]+b0[1]);
    t8[2]=f2b((x[kc][2]-mean)*inv*g0[2]+b0[2]); t8[3]=f2b((x[kc][3]-mean)*inv*g0[3]+b0[3]);
    t8[4]=f2b((x[kc][4]-mean)*inv*g1[0]+b1[0]); t8[5]=f2b((x[kc][5]-mean)*inv*g1[1]+b1[1]);
    t8[6]=f2b((x[kc][6]-mean)*inv*g1[2]+b1[2]); t8[7]=f2b((x[kc][7]-mean)*inv*g1[3]+b1[3]);
    __builtin_memcpy(&af[kc], t8, 16);
  }
  const short* Wp[3] = {Wq, Wk, Wv};
  short* Op[3] = {Qo, Ko, Vo};
  for (int y = 0; y < 3; y++) {
    __syncthreads();                           // DMA y drained
    f32x4 acc[8] = {};
    mfma_core_regA(af, Ws, lane, acc);
    bool phi = (phi_mask >> y) & 1;
    float sc = (y == 0) ? qscale : 1.0f;
    short* OUT = Op[y] + (size_t)row*128 + lgrp*4;
    __syncthreads();                           // all waves done reading Ws
    if (y < 2) stage_W_async(Wp[y+1], Ws, wave, lane);
    #pragma unroll
    for (int ct = 0; ct < 8; ct++) {
      short t4[4];
      #pragma unroll
      for (int reg = 0; reg < 4; reg++) {
        float v = acc[ct][reg] * sc;
        if (phi) v = (v > 0.f) ? v + 1.0f : __expf(v);
        t4[reg] = f2b(v);
      }
      bf16x4 pk; __builtin_memcpy(&pk, t4, 8);
      *(bf16x4*)(OUT + ct*16) = pk;
    }
  }
}

// ---- shared MLP tail (transposed D); Fin read, Fout written ----
template<bool REGA>
__device__ __forceinline__ void mlp_tail(const bf16x8 af1[4], short* As, short* Ws,
                                         const short* __restrict__ W1,
                                         const short* __restrict__ W2,
                                         const float* __restrict__ g,
                                         const float* __restrict__ b,
                                         const float* __restrict__ Fin,
                                         float* __restrict__ Fout,
                                         int row0, int tid) {
  int wave = tid >> 6, lane = tid & 63;
  int lrow = lane & 15, lgrp = lane >> 4;
  int rl = wave*16 + lrow;
  int orow = row0 + rl;
  const float* Fri = Fin + (size_t)orow*128 + lgrp*4;
  float* Fro = Fout + (size_t)orow*128 + lgrp*4;
  f32x4 acc[8] = {};
  if (REGA) mfma_core_regA(af1, Ws, lane, acc);
  else      mfma_core_T(As, Ws, wave, lane, acc);
  f32x4 fnew[8];
  #pragma unroll
  for (int ct = 0; ct < 8; ct++) {
    f32x4 fv = *(const f32x4*)(Fri + ct*16);
    fnew[ct] = acc[ct] + fv;
  }
  float s = 0.f, sq = 0.f;
  #pragma unroll
  for (int ct = 0; ct < 8; ct++)
    #pragma unroll
    for (int reg = 0; reg < 4; reg++) { float x = fnew[ct][reg]; s += x; sq += x*x; }
  s += __shfl_xor(s, 16, 64); sq += __shfl_xor(sq, 16, 64);
  s += __shfl_xor(s, 32, 64); sq += __shfl_xor(sq, 32, 64);
  float mean = s * (1.f/128.f);
  float var  = sq * (1.f/128.f) - mean*mean;
  float inv  = rsqrtf(var + 1e-5f);
  __syncthreads();                         // all waves done with Ws (GEMM1)
  stage_W_async(W1, Ws, wave, lane);
  #pragma unroll
  for (int ct = 0; ct < 8; ct++) {
    short t4[4];
    #pragma unroll
    for (int reg = 0; reg < 4; reg++) {
      int c = ct*16 + lgrp*4 + reg;
      t4[reg] = f2b((fnew[ct][reg] - mean) * inv * g[c] + b[c]);
    }
    bf16x4 pk; __builtin_memcpy(&pk, t4, 8);
    int G = ct*2 + (lgrp >> 1);
    *(bf16x4*)(&As[rl*128 + ((G ^ (rl & 7))*8) + (lgrp & 1)*4]) = pk;
  }
  __syncthreads();                         // DMA W1 drained + As visible
  f32x4 acc2[8] = {};
  mfma_core_T(As, Ws, wave, lane, acc2);
  __syncthreads();                         // done reading Ws/As (GEMM2)
  stage_W_async(W2, Ws, wave, lane);
  #pragma unroll
  for (int ct = 0; ct < 8; ct++) {
    short t4[4];
    #pragma unroll
    for (int reg = 0; reg < 4; reg++) {
      float v = acc2[ct][reg];
      v = 0.5f*v*(1.0f + erff(v*0.70710678118654752f));
      t4[reg] = f2b(v);
    }
    bf16x4 pk; __builtin_memcpy(&pk, t4, 8);
    int G = ct*2 + (lgrp >> 1);
    *(bf16x4*)(&As[rl*128 + ((G ^ (rl & 7))*8) + (lgrp & 1)*4]) = pk;
  }
  __syncthreads();
  f32x4 acc3[8] = {};
  mfma_core_T(As, Ws, wave, lane, acc3);
  #pragma unroll
  for (int ct = 0; ct < 8; ct++) {
    f32x4 o = fnew[ct] + acc3[ct];
    *(f32x4*)(Fro + ct*16) = o;
  }
}

// cross-layer MLP: GEMM1 A-frags straight from global Msg; Fout may be d_out
__global__ __launch_bounds__(256) void k_mlp(const short* __restrict__ Msg,
                                             const short* __restrict__ Wm,
                                             const short* __restrict__ W1,
                                             const short* __restrict__ W2,
                                             const float* __restrict__ g,
                                             const float* __restrict__ b,
                                             const float* __restrict__ Fin,
                                             float* __restrict__ Fout) {
  __shared__ short As[64*128];
  __shared__ short Ws[128*128];
  int tid = threadIdx.x;
  int row0 = blockIdx.x * 64;
  int wave = tid >> 6, lane = tid & 63;
  int lgrp = lane >> 4;
  int row = row0 + wave*16 + (lane & 15);
  stage_W_async(Wm, Ws, wave, lane);
  bf16x8 af1[4];
  const short* mr = Msg + (size_t)row*128;
  #pragma unroll
  for (int kc = 0; kc < 4; kc++)
    af1[kc] = *(const bf16x8*)(mr + kc*32 + lgrp*8);
  __syncthreads();
  mlp_tail<true>(af1, As, Ws, W1, W2, g, b, Fin, Fout, row0, tid);
}

// self-layer MLP: kvp chunk-reduce + linear-attention apply fused in
__global__ __launch_bounds__(256) void k_mlp_self(const short* __restrict__ Q,
                                                  const float* __restrict__ kvp,
                                                  const short* __restrict__ Wm,
                                                  const short* __restrict__ W1,
                                                  const short* __restrict__ W2,
                                                  const float* __restrict__ g,
                                                  const float* __restrict__ b,
                                                  float* __restrict__ F) {
  __shared__ short As[64*128];
  __shared__ short Ws[128*128];
  __shared__ float kvs[8*273];
  int tid = threadIdx.x;
  int row0 = blockIdx.x * 64;
  int n = row0 / SEQ;
  stage_W_async(Wm, Ws, tid >> 6, tid & 63);
  for (int i = tid; i < 8*272; i += 256) {
    int h = i / 272, j = i % 272;
    const float* src = kvp + ((size_t)(n*8 + h)*NCHUNK)*272 + j;
    float s = 0.f;
    #pragma unroll
    for (int c2 = 0; c2 < NCHUNK; c2++) s += src[(size_t)c2*272];
    kvs[h*273 + j] = s;
  }
  __syncthreads();
  int r = tid >> 2, qq = tid & 3;
  const short* qr = Q + (size_t)(row0 + r)*128;
  #pragma unroll
  for (int hh = 0; hh < 2; hh++) {
    int h = qq*2 + hh;
    bf16x8 q0 = *(const bf16x8*)(qr + h*16);
    bf16x8 q1 = *(const bf16x8*)(qr + h*16 + 8);
    float q[16];
    #pragma unroll
    for (int j = 0; j < 8; j++) { q[j] = b2f(q0[j]); q[8+j] = b2f(q1[j]); }
    const float* kvh = kvs + h*273;
    float z = 1e-6f;
    #pragma unroll
    for (int d = 0; d < 16; d++) z += q[d] * kvh[256 + d];
    float invz = 1.f / z;
    short o16[16];
    #pragma unroll
    for (int d2 = 0; d2 < 16; d2++) {
      float o = 0.f;
      #pragma unroll
      for (int d = 0; d < 16; d++) o += q[d] * kvh[d*16 + d2];
      o16[d2] = f2b(o * invz);
    }
    bf16x8 lo, hi; __builtin_memcpy(&lo, o16, 16); __builtin_memcpy(&hi, o16+8, 16);
    *(bf16x8*)(&As[r*128 + (((2*h)   ^ (r & 7))*8)]) = lo;
    *(bf16x8*)(&As[r*128 + (((2*h+1) ^ (r & 7))*8)]) = hi;
  }
  __syncthreads();
  mlp_tail<false>(nullptr, As, Ws, W1, W2, g, b, F, F, row0, tid);
}

// ---------------- linear attention: KV partial reduce (64-row coalesced tiles) ----
__global__ __launch_bounds__(256) void k_linred(const short* __restrict__ K,
                                                const short* __restrict__ V,
                                                float* __restrict__ kvp) {
  int nh = blockIdx.x;
  int n = nh >> 3, h = nh & 7;
  int chunk = blockIdx.y;
  int r0 = chunk * (SEQ / NCHUNK);          // 512 rows per chunk
  __shared__ float ks[64][17], vs[64][17];
  int tid = threadIdx.x;
  int d1 = tid >> 4, d2 = tid & 15;
  int rr = tid >> 2, q = tid & 3;
  float kv = 0.f, ksum = 0.f;
  for (int r = r0; r < r0 + SEQ/NCHUNK; r += 64) {
    __syncthreads();
    bf16x4 kk = *(const bf16x4*)(K + (size_t)(n*SEQ + r + rr)*128 + h*16 + q*4);
    bf16x4 vv = *(const bf16x4*)(V + (size_t)(n*SEQ + r + rr)*128 + h*16 + q*4);
    #pragma unroll
    for (int j = 0; j < 4; j++) { ks[rr][q*4+j] = b2f(kk[j]); vs[rr][q*4+j] = b2f(vv[j]); }
    __syncthreads();
    #pragma unroll
    for (int j = 0; j < 64; j++) {
      float kvl = ks[j][d1];
      kv   += kvl * vs[j][d2];
      ksum += kvl;
    }
  }
  float* dst = kvp + ((size_t)nh*NCHUNK + chunk)*272;
  dst[d1*16 + d2] = kv;
  if (d2 == 0) dst[256 + d1] = ksum;
}

// ------- full attention: 8 waves x 1 head; coalesced raw; XCD-aware swizzle ----
// flat grid 768; xcd = flat&7 gets 24 (side,n) groups x 4 parts -> K/V L2-local.
__global__ __launch_bounds__(512, 4) void k_fullattn(const short* __restrict__ Q,
                                                     const short* __restrict__ K,
                                                     const short* __restrict__ V,
                                                     short* __restrict__ MSG,
                                                     float* __restrict__ AL,
                                                     float* __restrict__ AR,
                                                     int first) {
  __shared__ __attribute__((aligned(16))) char smem[4*RB_G*4];  // 50.2KB union
  short* Vsub = (short*)smem;
  float* rawb = (float*)smem;
  int flat = blockIdx.x;
  int xcd = flat & 7, slot = flat >> 3;      // slot 0..95
  int group = xcd*24 + (slot >> 2);          // 0..191
  int part = slot & 3;
  int side = group >= 96 ? 1 : 0;
  int n = group - side*96;
  int qbase = side*HALF_R + n*192;
  int kbase = (side^1)*HALF_R + n*192;
  float* rawbase = (side ? AR : AL) + (size_t)n*192*192;
  int tid = threadIdx.x;
  int wave = tid >> 6, lane = tid & 63;   // wave = head
  int lrow = lane & 15, lgrp = lane >> 4;

  #pragma unroll
  for (int i = 0; i < 6; i++) {
    int c = tid + 512*i;
    int s = c >> 4, t8 = c & 15;
    bf16x8 v8 = *(const bf16x8*)(V + (size_t)(kbase + s)*128 + t8*8);
    *(bf16x8*)(&Vsub[(t8 >> 1)*VSTRIDE + s*16 + (t8 & 1)*8]) = v8;
  }
  __syncthreads();

  bf16x4 vf[12];
  {
    unsigned va = (unsigned)(uintptr_t)(&Vsub[0]) + wave*(VSTRIDE*2) + lane*8;
    TR_READ12(vf[0], vf[1], vf[2], vf[3], vf[4], vf[5],
              vf[6], vf[7], vf[8], vf[9], vf[10], vf[11], va);
  }
  __builtin_amdgcn_sched_barrier(0);
  bf16x4 kfr[12];
  #pragma unroll
  for (int st = 0; st < 12; st++)
    kfr[st] = *(const bf16x4*)(K + (size_t)(kbase + st*16 + lrow)*128
                                 + wave*16 + lgrp*4);
  __syncthreads();                   // Vsub consumed; smem becomes rawb

  const f32x4 z4 = {0.f, 0.f, 0.f, 0.f};
  int g = wave & 3;
  for (int li = 0; li < 3; li++) {
    int l0 = (part*3 + li)*16;
    bf16x4 qf = *(const bf16x4*)(Q + (size_t)(qbase + l0 + lrow)*128 + wave*16 + lgrp*4);
    f32x4 sa[12];
    #pragma unroll
    for (int st = 0; st < 12; st++)
      sa[st] = mfma16k16(kfr[st], qf, z4);
    float m = -1e30f;
    #pragma unroll
    for (int st = 0; st < 12; st++)
      m = fmaxf(m, fmaxf(fmaxf(sa[st][0], sa[st][1]), fmaxf(sa[st][2], sa[st][3])));
    m = fmaxf(m, __shfl_xor(m, 16, 64));
    m = fmaxf(m, __shfl_xor(m, 32, 64));
    float sum = 0.f;
    #pragma unroll
    for (int st = 0; st < 12; st++) {
      #pragma unroll
      for (int r = 0; r < 4; r++) {
        float p = __expf(sa[st][r] - m);
        sa[st][r] = p; sum += p;
      }
    }
    sum += __shfl_xor(sum, 16, 64);
    sum += __shfl_xor(sum, 32, 64);
    float inv = 1.f / sum;
    #pragma unroll
    for (int st = 0; st < 12; st++) {
      sa[st][0] *= inv; sa[st][1] *= inv; sa[st][2] *= inv; sa[st][3] *= inv;
    }
    {
      f32x4 o = z4;
      #pragma unroll
      for (int st = 0; st < 12; st++) {
        bf16x4 pf;
        pf[0] = f2b(sa[st][0]); pf[1] = f2b(sa[st][1]);
        pf[2] = f2b(sa[st][2]); pf[3] = f2b(sa[st][3]);
        o = mfma16k16(vf[st], pf, o);
      }
      bf16x4 o4;
      o4[0] = f2b(o[0]); o4[1] = f2b(o[1]); o4[2] = f2b(o[2]); o4[3] = f2b(o[3]);
      *(bf16x4*)(MSG + (size_t)(qbase + l0 + lrow)*128 + wave*16 + lgrp*4) = o4;
    }
    // raw partials: thread (lrow,lgrp) holds s-group grp = st*4+lgrp of row lrow
    if (wave < 4) {
      #pragma unroll
      for (int st = 0; st < 12; st++)
        *(f32x4*)(&rawb[g*RB_G + (lrow*49 + st*4 + lgrp)*4]) = sa[st];
    }
    __syncthreads();
    if (wave >= 4) {
      #pragma unroll
      for (int st = 0; st < 12; st++) {
        f32x4* slot2 = (f32x4*)(&rawb[g*RB_G + (lrow*49 + st*4 + lgrp)*4]);
        *slot2 = *slot2 + sa[st];
      }
    }
    __syncthreads();
    // reduce 4 groups -> global; slot = row*48 + grp (coalesced 16B stores)
    #pragma unroll
    for (int i = 0; i < 2; i++) {
      int sl = tid + 512*i;
      if (sl < 768) {
        int row = sl / 48, grp = sl - row*48;
        int off = (row*49 + grp)*4;
        f32x4 a = *(const f32x4*)(&rawb[0*RB_G + off]);
        f32x4 b = *(const f32x4*)(&rawb[1*RB_G + off]);
        f32x4 c = *(const f32x4*)(&rawb[2*RB_G + off]);
        f32x4 d = *(const f32x4*)(&rawb[3*RB_G + off]);
        f32x4 t = (a + b) + (c + d);
        float* gp = rawbase + (size_t)(l0 + row)*192 + grp*4;
        if (first) {
          *(f32x4*)gp = t;
        } else {
          f32x4 cur = *(const f32x4*)gp;
          *(f32x4*)gp = cur + t;
        }
      }
    }
    __syncthreads();
  }
}

// ---------------- launch ----------------
extern "C" void kernel_launch(void* const* d_in, const int* in_sizes, int n_in,
                              void* d_out, int out_size, void* d_ws, size_t ws_size,
                              hipStream_t stream) {
  const float* feat_l = (const float*)d_in[0];
  const float* feat_r = (const float*)d_in[1];
  const float* attn_l = (const float*)d_in[2];
  const float* attn_r = (const float*)d_in[3];
  const float* saw[6] = { (const float*)d_in[4],  (const float*)d_in[6],  (const float*)d_in[8],
                          (const float*)d_in[10], (const float*)d_in[12], (const float*)d_in[14] };
  const float* caw[6] = { (const float*)d_in[5],  (const float*)d_in[7],  (const float*)d_in[9],
                          (const float*)d_in[11], (const float*)d_in[13], (const float*)d_in[15] };
  const float* sa_n1g = (const float*)d_in[16]; const float* ca_n1g = (const float*)d_in[17];
  const float* sa_n1b = (const float*)d_in[18]; const float* ca_n1b = (const float*)d_in[19];
  const float* sa_n2g = (const float*)d_in[20]; const float* ca_n2g = (const float*)d_in[21];
  const float* sa_n2b = (const float*)d_in[22]; const float* ca_n2b = (const float*)d_in[23];

  float* F   = (float*)d_ws;
  float* ALa = F + NE;
  float* ARa = ALa + ATTN_E;
  float* KVp = ARa + ATTN_E;                   // 32*NCHUNK*272
  short* WB  = (short*)(KVp + 32*NCHUNK*272);
  short* Qb  = WB + 12*6*16384;
  short* Kb  = Qb + NE;
  short* Vb  = Kb + NE;
  short* Mb  = Vb + NE;

  float* out = (float*)d_out;

  k_w2b<<<dim3(48,12), 256, 0, stream>>>(saw[0],saw[1],saw[2],saw[3],saw[4],saw[5],
                                         caw[0],caw[1],caw[2],caw[3],caw[4],caw[5], WB);
  k_copy<<<1024, 256, 0, stream>>>(feat_l, F, NE/2);
  k_copy<<<1024, 256, 0, stream>>>(feat_r, F + NE/2, NE/2);

  for (int i = 0; i < 6; i++) {
    const short* sw[6], *cw[6];
    for (int t = 0; t < 6; t++) { sw[t] = WB + (size_t)(t*6 + i)*16384; cw[t] = WB + (size_t)((6+t)*6 + i)*16384; }
    int vo = i*128;
    // ---- self layer ----
    k_qkv3<<<576, 256, 0, stream>>>(F, sw[0], sw[1], sw[2], sa_n1g+vo, sa_n1b+vo,
                                    Qb, Kb, Vb, 0b011, 1.0f);
    k_linred<<<dim3(32, NCHUNK), 256, 0, stream>>>(Kb, Vb, KVp);
    k_mlp_self<<<576, 256, 0, stream>>>(Qb, KVp, sw[3], sw[4], sw[5],
                                        sa_n2g+vo, sa_n2b+vo, F);
    // ---- cross layer ----
    k_qkv3<<<576, 256, 0, stream>>>(F, cw[0], cw[1], cw[2], ca_n1g+vo, ca_n1b+vo,
                                    Qb, Kb, Vb, 0, 0.25f);
    k_fullattn<<<768, 512, 0, stream>>>(Qb, Kb, Vb, Mb, ALa, ARa, i == 0 ? 1 : 0);
    k_mlp<<<576, 256, 0, stream>>>(Mb, cw[3], cw[4], cw[5], ca_n2g+vo, ca_n2b+vo,
                                   F, (i == 5) ? out : F);
  }

  k_addf<<<2048, 256, 0, stream>>>(attn_l, ALa, out + NE, ATTN_E);
  k_addf<<<2048, 256, 0, stream>>>(attn_r, ARa, out + NE + ATTN_E, ATTN_E);
}